// Round 7
// baseline (346.805 us; speedup 1.0000x reference)
//
#include <hip/hip_runtime.h>
#include <math.h>

// ---------------------------------------------------------------------------
// Mamba forward. All GEMMs bf16 MFMA; conv + scan fp32 compute, bf16 storage.
// Round-7: (1) swapped MFMA operand order in all GEMMs -> each thread holds 4
// consecutive n -> vectorized epilogue stores (float4 / u16x4);
// (2) XOR-swizzled LDS staging (chunk ^ ((row>>1)&3)) -> 2-way bank aliasing
// (free) instead of 8-way; (3) delta stored bf16.
// ---------------------------------------------------------------------------

#define DMODEL 1024
#define DINNER 2048
#define DSTATE 16
#define DTRANK 64
#define BSZ    2
#define LSEQ   2048
#define NCHUNK 64
#define CLEN   32
#define SPLITK 16
#define KCH    (DINNER / SPLITK)   // 128
#define XDBL_N 96
#define XDBL_SZ (BSZ*LSEQ*XDBL_N)  // 393216
#define NROW16 (BSZ*DINNER*DSTATE) // 65536 state rows

typedef __attribute__((ext_vector_type(8))) short bf16x8;
typedef __attribute__((ext_vector_type(8))) unsigned short u16x8;
typedef __attribute__((ext_vector_type(4))) unsigned short u16x4;
typedef __attribute__((ext_vector_type(4))) float f32x4;

__device__ __forceinline__ float silu_f(float v) {
    return v / (1.f + __expf(-v));
}
__device__ __forceinline__ float softplus_f(float v) {
    return (v > 20.f) ? v : log1pf(expf(v));
}
__device__ __forceinline__ unsigned short f2bf(float f) {
    unsigned int u = __float_as_uint(f);
    unsigned int r = (u + 0x7fffu + ((u >> 16) & 1u)) >> 16;   // RNE
    return (unsigned short)r;
}
__device__ __forceinline__ float bf2f(unsigned short u) {
    return __uint_as_float(((unsigned int)u) << 16);
}
__device__ __forceinline__ void gl_lds16(const void* g, void* l) {
    __builtin_amdgcn_global_load_lds(
        (const __attribute__((address_space(1))) unsigned int*)g,
        (__attribute__((address_space(3))) unsigned int*)l, 16, 0, 0);
}
__device__ __forceinline__ void cast8(const float* __restrict__ src,
                                      unsigned short* __restrict__ dst, size_t i) {
    float4 a = ((const float4*)src)[2 * i];
    float4 b = ((const float4*)src)[2 * i + 1];
    u16x8 v;
    v[0] = f2bf(a.x); v[1] = f2bf(a.y); v[2] = f2bf(a.z); v[3] = f2bf(a.w);
    v[4] = f2bf(b.x); v[5] = f2bf(b.y); v[6] = f2bf(b.z); v[7] = f2bf(b.w);
    *(u16x8*)(dst + 8 * i) = v;
}

// ---------------------------------------------------------------------------
// K0: all weight/input casts in one launch. Block ranges (8 elems/thread):
//  [0,2048) hidden ; [2048,4096) in_proj_w ; [4096,5120) out_proj_w ;
//  [5120,5184) dt_proj_w ; [5184,5312) x_proj_w -> 128-row padded dst
// ---------------------------------------------------------------------------
__global__ __launch_bounds__(256) void cast_all(
    const float* __restrict__ hidden, const float* __restrict__ ipw,
    const float* __restrict__ opw, const float* __restrict__ dtw,
    const float* __restrict__ xpw,
    unsigned short* __restrict__ hbf, unsigned short* __restrict__ wbf,
    unsigned short* __restrict__ owbf, unsigned short* __restrict__ dtwbf,
    unsigned short* __restrict__ xpwbf)
{
    int bid = blockIdx.x;
    if (bid < 2048) {
        cast8(hidden, hbf, (size_t)bid * 256 + threadIdx.x);
    } else if (bid < 4096) {
        cast8(ipw, wbf, (size_t)(bid - 2048) * 256 + threadIdx.x);
    } else if (bid < 5120) {
        cast8(opw, owbf, (size_t)(bid - 4096) * 256 + threadIdx.x);
    } else if (bid < 5184) {
        cast8(dtw, dtwbf, (size_t)(bid - 5120) * 256 + threadIdx.x);
    } else {
        size_t i = (size_t)(bid - 5184) * 256 + threadIdx.x;
        size_t o = i * 8;
        int row = (int)(o >> 11);
        u16x8 v = {0, 0, 0, 0, 0, 0, 0, 0};
        if (row < 96) {
            float4 a = ((const float4*)xpw)[2 * i];
            float4 b = ((const float4*)xpw)[2 * i + 1];
            v[0] = f2bf(a.x); v[1] = f2bf(a.y); v[2] = f2bf(a.z); v[3] = f2bf(a.w);
            v[4] = f2bf(b.x); v[5] = f2bf(b.y); v[6] = f2bf(b.z); v[7] = f2bf(b.w);
        }
        *(u16x8*)(xpwbf + o) = v;
    }
}

// ---------------------------------------------------------------------------
// bf16 MFMA GEMM (NT): C[m,n] = sum_k A[m,k]*B[n,k]
// 128x128 tile, BK=32, 4 waves. Swapped-operand MFMA: thread holds
// m = tile_m + l16, n = tile_n + quad*4..+3 (contiguous) -> vector stores.
// LDS XOR swizzle: slot(row,c) holds global chunk c ^ ((row>>1)&3).
// EPI 1: n<DINNER -> xb bf16 ; else zb bf16
// EPI 2: xb bf16 = softplus(acc + bias[n])
// ---------------------------------------------------------------------------
template<int EPI>
__global__ __launch_bounds__(256) void gemm_bf16(
    const short* __restrict__ A, const short* __restrict__ B,
    unsigned short* __restrict__ xb, unsigned short* __restrict__ zb,
    const float* __restrict__ bias, int K)
{
    __shared__ __align__(16) short As[128 * 32];
    __shared__ __align__(16) short Bs[128 * 32];
    const int t = threadIdx.x;
    const int wave = t >> 6, lane = t & 63;
    const int m0 = blockIdx.y * 128, n0 = blockIdx.x * 128;
    const int wm = (wave & 1) * 64, wn = (wave >> 1) * 64;
    const int srow = t >> 2;
    const int sq = (((t & 3) ^ ((t >> 3) & 3)) * 16);   // swizzled source chunk

    const short* Ag = A + (size_t)(m0 + srow) * K;
    const short* Bg = B + (size_t)(n0 + srow) * K;
    char* AsL0 = (char*)As + wave * 1024;
    char* AsL1 = (char*)As + 4096 + wave * 1024;
    char* BsL0 = (char*)Bs + wave * 1024;
    char* BsL1 = (char*)Bs + 4096 + wave * 1024;

    const int quad = lane >> 4, l16 = lane & 15;
    const int swz = (l16 >> 1) & 3;
    const int qs = (quad ^ swz) * 8;
    const int aoff = (wm + l16) * 32 + qs;
    const int boff = (wn + l16) * 32 + qs;

    f32x4 acc[4][4];
#pragma unroll
    for (int i = 0; i < 4; i++)
#pragma unroll
        for (int j = 0; j < 4; j++) {
            f32x4 z = {0.f, 0.f, 0.f, 0.f};
            acc[i][j] = z;
        }

    for (int k0 = 0; k0 < K; k0 += 32) {
        __syncthreads();
        gl_lds16((const char*)(Ag + k0) + sq, AsL0);
        gl_lds16((const char*)(Ag + (size_t)64 * K + k0) + sq, AsL1);
        gl_lds16((const char*)(Bg + k0) + sq, BsL0);
        gl_lds16((const char*)(Bg + (size_t)64 * K + k0) + sq, BsL1);
        __syncthreads();
        bf16x8 af[4], bfr[4];
#pragma unroll
        for (int i = 0; i < 4; i++) {
            af[i]  = *(const bf16x8*)(As + aoff + i * 16 * 32);
            bfr[i] = *(const bf16x8*)(Bs + boff + i * 16 * 32);
        }
        // swapped operands: D[n-block via quad*4+r][m via l16]
#pragma unroll
        for (int i = 0; i < 4; i++)
#pragma unroll
            for (int j = 0; j < 4; j++)
                acc[i][j] = __builtin_amdgcn_mfma_f32_16x16x32_bf16(
                    bfr[j], af[i], acc[i][j], 0, 0, 0);
    }

#pragma unroll
    for (int i = 0; i < 4; i++) {
        int m = m0 + wm + i * 16 + l16;
#pragma unroll
        for (int j = 0; j < 4; j++) {
            int n = n0 + wn + j * 16 + quad * 4;
            if (EPI == 1) {
                unsigned short* dst = (n0 < DINNER) ? xb : zb;
                int nn = (n0 < DINNER) ? n : (n - DINNER);
                u16x4 o;
#pragma unroll
                for (int r = 0; r < 4; r++) o[r] = f2bf(acc[i][j][r]);
                *(u16x4*)(dst + (size_t)m * DINNER + nn) = o;
            } else {   // EPI == 2
                float4 bv = *(const float4*)(bias + n);
                u16x4 o;
                o[0] = f2bf(softplus_f(acc[i][j][0] + bv.x));
                o[1] = f2bf(softplus_f(acc[i][j][1] + bv.y));
                o[2] = f2bf(softplus_f(acc[i][j][2] + bv.z));
                o[3] = f2bf(softplus_f(acc[i][j][3] + bv.w));
                *(u16x4*)(xb + (size_t)m * DINNER + n) = o;
            }
        }
    }
}

// ---------------------------------------------------------------------------
// K8: 128M x 64N tile, BK=32, 4 waves (each 32M x 64N). 512 blocks.
// Swapped operands + swizzled LDS; float4 epilogue.
// ---------------------------------------------------------------------------
__global__ __launch_bounds__(256) void gemm_n64(
    const short* __restrict__ A, const short* __restrict__ B,
    float* __restrict__ C, int ldc, int K)
{
    __shared__ __align__(16) short As[128 * 32];
    __shared__ __align__(16) short Bs[64 * 32];
    const int t = threadIdx.x;
    const int wave = t >> 6, lane = t & 63;
    const int m0 = blockIdx.y * 128, n0 = blockIdx.x * 64;
    const int wm = wave * 32;
    const int srow = t >> 2;
    const int sq = (((t & 3) ^ ((t >> 3) & 3)) * 16);

    const short* Ag = A + (size_t)(m0 + srow) * K;
    const short* Bg = B + (size_t)(n0 + srow) * K;
    char* AsL0 = (char*)As + wave * 1024;
    char* AsL1 = (char*)As + 4096 + wave * 1024;
    char* BsL0 = (char*)Bs + wave * 1024;

    const int quad = lane >> 4, l16 = lane & 15;
    const int swz = (l16 >> 1) & 3;
    const int qs = (quad ^ swz) * 8;

    f32x4 acc[2][4];
#pragma unroll
    for (int i = 0; i < 2; i++)
#pragma unroll
        for (int j = 0; j < 4; j++) {
            f32x4 z = {0.f, 0.f, 0.f, 0.f};
            acc[i][j] = z;
        }

    for (int k0 = 0; k0 < K; k0 += 32) {
        __syncthreads();
        gl_lds16((const char*)(Ag + k0) + sq, AsL0);
        gl_lds16((const char*)(Ag + (size_t)64 * K + k0) + sq, AsL1);
        gl_lds16((const char*)(Bg + k0) + sq, BsL0);
        __syncthreads();
        bf16x8 af[2], bfr[4];
#pragma unroll
        for (int i = 0; i < 2; i++)
            af[i] = *(const bf16x8*)(As + (wm + i * 16 + l16) * 32 + qs);
#pragma unroll
        for (int j = 0; j < 4; j++)
            bfr[j] = *(const bf16x8*)(Bs + (j * 16 + l16) * 32 + qs);
#pragma unroll
        for (int i = 0; i < 2; i++)
#pragma unroll
            for (int j = 0; j < 4; j++)
                acc[i][j] = __builtin_amdgcn_mfma_f32_16x16x32_bf16(
                    bfr[j], af[i], acc[i][j], 0, 0, 0);
    }

#pragma unroll
    for (int i = 0; i < 2; i++) {
        int m = m0 + wm + i * 16 + l16;
#pragma unroll
        for (int j = 0; j < 4; j++) {
            int n = n0 + j * 16 + quad * 4;
            float4 v = make_float4(acc[i][j][0], acc[i][j][1],
                                   acc[i][j][2], acc[i][j][3]);
            *(float4*)(C + (size_t)m * ldc + n) = v;
        }
    }
}

// ---------------------------------------------------------------------------
// K3: x_dbl split-K MFMA. grid (32, SPLITK). Partials -> ppart[kc][4096][96].
// Swapped operands + swizzled LDS; float4 epilogue.
// ---------------------------------------------------------------------------
__global__ __launch_bounds__(256) void gemm_xproj(
    const short* __restrict__ Abf, const short* __restrict__ Bbf,
    float* __restrict__ ppart)
{
    __shared__ __align__(16) short As[128 * 32];
    __shared__ __align__(16) short Bs[128 * 32];
    const int t = threadIdx.x;
    const int wave = t >> 6, lane = t & 63;
    const int m0 = blockIdx.x * 128;
    const int kc = blockIdx.y;
    const int srow = t >> 2;
    const int sq = (((t & 3) ^ ((t >> 3) & 3)) * 16);

    const short* Ag = Abf + (size_t)(m0 + srow) * DINNER;
    const short* Bg = Bbf + (size_t)srow * DINNER;
    char* AsL0 = (char*)As + wave * 1024;
    char* AsL1 = (char*)As + 4096 + wave * 1024;
    char* BsL0 = (char*)Bs + wave * 1024;
    char* BsL1 = (char*)Bs + 4096 + wave * 1024;

    const int quad = lane >> 4, l16 = lane & 15;
    const int swz = (l16 >> 1) & 3;
    const int qs = (quad ^ swz) * 8;
    const int wm = wave * 32;

    f32x4 acc[2][6];
#pragma unroll
    for (int i = 0; i < 2; i++)
#pragma unroll
        for (int j = 0; j < 6; j++) {
            f32x4 z = {0.f, 0.f, 0.f, 0.f};
            acc[i][j] = z;
        }

    for (int k0 = kc * KCH; k0 < kc * KCH + KCH; k0 += 32) {
        __syncthreads();
        gl_lds16((const char*)(Ag + k0) + sq, AsL0);
        gl_lds16((const char*)(Ag + (size_t)64 * DINNER + k0) + sq, AsL1);
        gl_lds16((const char*)(Bg + k0) + sq, BsL0);
        gl_lds16((const char*)(Bg + (size_t)64 * DINNER + k0) + sq, BsL1);
        __syncthreads();
        bf16x8 af[2], bfr[6];
#pragma unroll
        for (int i = 0; i < 2; i++)
            af[i] = *(const bf16x8*)(As + (wm + i * 16 + l16) * 32 + qs);
#pragma unroll
        for (int j = 0; j < 6; j++)
            bfr[j] = *(const bf16x8*)(Bs + (j * 16 + l16) * 32 + qs);
#pragma unroll
        for (int i = 0; i < 2; i++)
#pragma unroll
            for (int j = 0; j < 6; j++)
                acc[i][j] = __builtin_amdgcn_mfma_f32_16x16x32_bf16(
                    bfr[j], af[i], acc[i][j], 0, 0, 0);
    }

    float* dst = ppart + (size_t)kc * XDBL_SZ;
#pragma unroll
    for (int i = 0; i < 2; i++) {
        int m = m0 + wm + i * 16 + l16;
#pragma unroll
        for (int j = 0; j < 6; j++) {
            int n = j * 16 + quad * 4;
            float4 v = make_float4(acc[i][j][0], acc[i][j][1],
                                   acc[i][j][2], acc[i][j][3]);
            *(float4*)(dst + (size_t)m * XDBL_N + n) = v;
        }
    }
}

// also emits dt_lo (cols 0..63) as bf16 for the K4 MFMA
__global__ __launch_bounds__(256) void reduce_xdbl(
    const float* __restrict__ ppart, float* __restrict__ xdbl,
    unsigned short* __restrict__ dtlobf)
{
    int i = blockIdx.x * 256 + threadIdx.x;
    float s = 0.f;
#pragma unroll
    for (int c = 0; c < SPLITK; c++) s += ppart[(size_t)c * XDBL_SZ + i];
    xdbl[i] = s;
    int m = i / XDBL_N;
    int n = i - m * XDBL_N;
    if (n < DTRANK) dtlobf[(size_t)m * DTRANK + n] = f2bf(s);
}

// ---------------------------------------------------------------------------
// Causal conv4 + bias + SiLU, (b,l,ch) bf16 in, bf16 out. 4 ch per thread.
// ---------------------------------------------------------------------------
__global__ __launch_bounds__(256) void conv_silu(
    const unsigned short* __restrict__ xb, const float* __restrict__ convw,
    const float* __restrict__ convb, unsigned short* __restrict__ xtbf)
{
    int i = blockIdx.x * 256 + threadIdx.x;
    int c4 = i & 511;
    int m  = i >> 9;
    int l  = m & (LSEQ - 1);
    int ch = c4 * 4;
    const u16x4* base = (const u16x4*)xb + (size_t)m * 512 + c4;
    u16x4 vz = {0, 0, 0, 0};
    u16x4 v3 = base[0];
    u16x4 v2 = (l >= 1) ? base[-512]  : vz;
    u16x4 v1 = (l >= 2) ? base[-1024] : vz;
    u16x4 v0 = (l >= 3) ? base[-1536] : vz;
    float4 t0 = ((const float4*)convw)[ch + 0];
    float4 t1 = ((const float4*)convw)[ch + 1];
    float4 t2 = ((const float4*)convw)[ch + 2];
    float4 t3 = ((const float4*)convw)[ch + 3];
    float4 bv = ((const float4*)convb)[c4];
    u16x4 o;
    o[0] = f2bf(silu_f(bv.x + t0.x * bf2f(v0[0]) + t0.y * bf2f(v1[0]) +
                       t0.z * bf2f(v2[0]) + t0.w * bf2f(v3[0])));
    o[1] = f2bf(silu_f(bv.y + t1.x * bf2f(v0[1]) + t1.y * bf2f(v1[1]) +
                       t1.z * bf2f(v2[1]) + t1.w * bf2f(v3[1])));
    o[2] = f2bf(silu_f(bv.z + t2.x * bf2f(v0[2]) + t2.y * bf2f(v1[2]) +
                       t2.z * bf2f(v2[2]) + t2.w * bf2f(v3[2])));
    o[3] = f2bf(silu_f(bv.w + t3.x * bf2f(v0[3]) + t3.y * bf2f(v1[3]) +
                       t3.z * bf2f(v2[3]) + t3.w * bf2f(v3[3])));
    *(u16x4*)(xtbf + (size_t)m * DINNER + ch) = o;
}

// ---------------------------------------------------------------------------
// Chunked selective scan: thread = one (b,d,chunk), 16 states in registers.
// grid (DINNER/256, NCHUNK, BSZ) = 1024 blocks. B/C staged in LDS; per-step
// LDS reads are wave-uniform broadcast. Manual one-step load-ahead.
// delta now bf16.
// ---------------------------------------------------------------------------
__global__ __launch_bounds__(256) void scan_phaseA(
    const float* __restrict__ xdbl, const unsigned short* __restrict__ dltbf,
    const unsigned short* __restrict__ xtbf, const float* __restrict__ A_log,
    float* __restrict__ Pbuf, float* __restrict__ Sbuf)
{
    __shared__ float Bsh[CLEN][16];
    const int d = blockIdx.x * 256 + threadIdx.x;
    const int c = blockIdx.y, b = blockIdx.z;
    if (threadIdx.x < CLEN * 4) {
        int lr = threadIdx.x >> 2, p = threadIdx.x & 3;
        const float* src = xdbl +
            ((size_t)b * LSEQ + (size_t)c * CLEN + lr) * XDBL_N + DTRANK + p * 4;
        *(float4*)&Bsh[lr][p * 4] = *(const float4*)src;
    }
    __syncthreads();

    float A[16], P[16], S[16];
#pragma unroll
    for (int q = 0; q < 4; q++) {
        float4 a4 = *(const float4*)(A_log + d * DSTATE + q * 4);
        A[4 * q] = -__expf(a4.x); A[4 * q + 1] = -__expf(a4.y);
        A[4 * q + 2] = -__expf(a4.z); A[4 * q + 3] = -__expf(a4.w);
    }
#pragma unroll
    for (int j = 0; j < 16; j++) { P[j] = 1.f; S[j] = 0.f; }

    size_t off = ((size_t)b * LSEQ + (size_t)c * CLEN) * DINNER + d;
    float dvn = bf2f(dltbf[off]);
    float xvn = bf2f(xtbf[off]);
    for (int ll = 0; ll < CLEN; ++ll) {
        float dv = dvn, xv = xvn;
        if (ll + 1 < CLEN) {
            off += DINNER;
            dvn = bf2f(dltbf[off]);
            xvn = bf2f(xtbf[off]);
        }
        float dx = dv * xv;
        f32x4 Bq[4];
#pragma unroll
        for (int q = 0; q < 4; q++) Bq[q] = *(const f32x4*)&Bsh[ll][q * 4];
#pragma unroll
        for (int j = 0; j < 16; j++) {
            float dA = __expf(dv * A[j]);
            P[j] *= dA;
            S[j] = fmaf(dA, S[j], dx * Bq[j >> 2][j & 3]);
        }
    }
    size_t o = ((size_t)c * BSZ * DINNER + (size_t)b * DINNER + d) * 16;
#pragma unroll
    for (int q = 0; q < 4; q++) {
        *(float4*)(Pbuf + o + q * 4) =
            make_float4(P[4 * q], P[4 * q + 1], P[4 * q + 2], P[4 * q + 3]);
        *(float4*)(Sbuf + o + q * 4) =
            make_float4(S[4 * q], S[4 * q + 1], S[4 * q + 2], S[4 * q + 3]);
    }
}

__global__ __launch_bounds__(256) void scan_phaseB(
    const float* __restrict__ Pbuf, const float* __restrict__ Sbuf,
    float* __restrict__ Hbuf)
{
    int r = blockIdx.x * 256 + threadIdx.x;   // 65536 state rows
    float run = 0.f;
    for (int c = 0; c < NCHUNK; ++c) {
        size_t o = (size_t)c * NROW16 + r;
        Hbuf[o] = run;
        run = Pbuf[o] * run + Sbuf[o];
    }
}

__global__ __launch_bounds__(256) void scan_phaseC(
    const float* __restrict__ xdbl, const unsigned short* __restrict__ dltbf,
    const unsigned short* __restrict__ xtbf, const unsigned short* __restrict__ zbf,
    const float* __restrict__ A_log, const float* __restrict__ Dvec,
    const float* __restrict__ Hbuf, unsigned short* __restrict__ ybf)
{
    __shared__ float BCsh[CLEN][32];   // [l][0:16]=B, [l][16:32]=C
    const int d = blockIdx.x * 256 + threadIdx.x;
    const int c = blockIdx.y, b = blockIdx.z;
    {
        int lr = threadIdx.x >> 3, p = threadIdx.x & 7;
        const float* src = xdbl +
            ((size_t)b * LSEQ + (size_t)c * CLEN + lr) * XDBL_N + DTRANK;
        *(float4*)&BCsh[lr][p * 4] = *(const float4*)(src + p * 4);
    }
    __syncthreads();

    float A[16], h[16];
#pragma unroll
    for (int q = 0; q < 4; q++) {
        float4 a4 = *(const float4*)(A_log + d * DSTATE + q * 4);
        A[4 * q] = -__expf(a4.x); A[4 * q + 1] = -__expf(a4.y);
        A[4 * q + 2] = -__expf(a4.z); A[4 * q + 3] = -__expf(a4.w);
    }
    size_t o = ((size_t)c * BSZ * DINNER + (size_t)b * DINNER + d) * 16;
#pragma unroll
    for (int q = 0; q < 4; q++) {
        float4 h4 = *(const float4*)(Hbuf + o + q * 4);
        h[4 * q] = h4.x; h[4 * q + 1] = h4.y;
        h[4 * q + 2] = h4.z; h[4 * q + 3] = h4.w;
    }
    float Dd = Dvec[d];
    size_t off = ((size_t)b * LSEQ + (size_t)c * CLEN) * DINNER + d;
    float dvn = bf2f(dltbf[off]);
    float xvn = bf2f(xtbf[off]);
    float zvn = bf2f(zbf[off]);
    size_t offc = off;
    for (int ll = 0; ll < CLEN; ++ll) {
        float dv = dvn, xv = xvn, zv = zvn;
        size_t offw = offc;
        if (ll + 1 < CLEN) {
            offc += DINNER;
            dvn = bf2f(dltbf[offc]);
            xvn = bf2f(xtbf[offc]);
            zvn = bf2f(zbf[offc]);
        }
        float dx = dv * xv;
        f32x4 Bq[4], Cq[4];
#pragma unroll
        for (int q = 0; q < 4; q++) {
            Bq[q] = *(const f32x4*)&BCsh[ll][q * 4];
            Cq[q] = *(const f32x4*)&BCsh[ll][16 + q * 4];
        }
        float yp = 0.f;
#pragma unroll
        for (int j = 0; j < 16; j++) {
            float dA = __expf(dv * A[j]);
            h[j] = fmaf(dA, h[j], dx * Bq[j >> 2][j & 3]);
            yp = fmaf(h[j], Cq[j >> 2][j & 3], yp);
        }
        float yv = yp + Dd * xv;
        yv *= zv / (1.f + __expf(-zv));
        ybf[offw] = f2bf(yv);
    }
}

// ---------------------------------------------------------------------------
extern "C" void kernel_launch(void* const* d_in, const int* in_sizes, int n_in,
                              void* d_out, int out_size, void* d_ws, size_t ws_size,
                              hipStream_t stream)
{
    const float* hidden     = (const float*)d_in[0];
    const float* in_proj_w  = (const float*)d_in[1];
    const float* conv_w     = (const float*)d_in[2];
    const float* conv_b     = (const float*)d_in[3];
    const float* x_proj_w   = (const float*)d_in[4];
    const float* dt_proj_w  = (const float*)d_in[5];
    const float* dt_proj_b  = (const float*)d_in[6];
    const float* A_log      = (const float*)d_in[7];
    const float* Dvec       = (const float*)d_in[8];
    const float* out_proj_w = (const float*)d_in[9];
    float* out = (float*)d_out;

    // workspace (float units), 35 MF = 140 MB:
    //  [0,4)      xbf (bf16, K1->K2) / dltbf (bf16, K4->scan)  [disjoint]
    //  [8,12)     zbf  (bf16)
    //  [12,16)    xtbf (bf16)
    //  [16,20)    Pbuf ; [20,24) Sbuf ; [24,28) Hbuf
    //             ppart aliases [16,22) (K3->reduce, before scan)
    //  [28,28.125)  xpwbf ; [28.25,28.625) xdbl fp32
    //  [29,30)    owbf ; [30,30.0625) dtwbf ; [30.25,30.375) dtlobf
    //  [31,33)    hbf ; [33,35) wbf ; ybf aliases [31,35)
    const size_t MF = 1024 * 1024;
    float* ws = (float*)d_ws;
    unsigned short* xbf   = (unsigned short*)ws;
    unsigned short* dltbf = (unsigned short*)ws;
    unsigned short* zbf  = (unsigned short*)(ws + 8 * MF);
    unsigned short* xtbf = (unsigned short*)(ws + 12 * MF);
    float* Pbuf  = ws + 16 * MF;
    float* Sbuf  = ws + 20 * MF;
    float* Hbuf  = ws + 24 * MF;
    float* ppart = ws + 16 * MF;
    unsigned short* xpwbf  = (unsigned short*)(ws + 28 * MF);
    float* xdbl  = ws + 28 * MF + MF / 4;
    unsigned short* owbf   = (unsigned short*)(ws + 29 * MF);
    unsigned short* dtwbf  = (unsigned short*)(ws + 30 * MF);
    unsigned short* dtlobf = (unsigned short*)(ws + 30 * MF + MF / 4);
    unsigned short* hbf    = (unsigned short*)(ws + 31 * MF);
    unsigned short* wbf    = (unsigned short*)(ws + 33 * MF);
    unsigned short* ybf    = hbf;   // reused after K1

    const int M = BSZ * LSEQ;   // 4096

    // K0: all casts
    cast_all<<<5312, 256, 0, stream>>>(hidden, in_proj_w, out_proj_w,
                                       dt_proj_w, x_proj_w,
                                       hbf, wbf, owbf, dtwbf, xpwbf);

    // K1: xz = hidden @ in_proj_w^T (bf16 MFMA) -> xbf, zbf (both bf16)
    gemm_bf16<1><<<dim3(2 * DINNER / 128, M / 128), 256, 0, stream>>>(
        (const short*)hbf, (const short*)wbf, xbf, zbf, nullptr, DMODEL);

    // K2: conv + SiLU (bf16 -> bf16)
    conv_silu<<<(M * 512) / 256, 256, 0, stream>>>(xbf, conv_w, conv_b, xtbf);

    // K3: x_dbl split-K MFMA + reduce (emits fp32 xdbl + bf16 dt_lo)
    gemm_xproj<<<dim3(M / 128, SPLITK), 256, 0, stream>>>(
        (const short*)xtbf, (const short*)xpwbf, ppart);
    reduce_xdbl<<<XDBL_SZ / 256, 256, 0, stream>>>(ppart, xdbl, dtlobf);

    // K4: delta = softplus(dt_lo @ dt_proj_w^T + dt_proj_b) -> bf16 dltbf
    gemm_bf16<2><<<dim3(DINNER / 128, M / 128), 256, 0, stream>>>(
        (const short*)dtlobf, (const short*)dtwbf, dltbf, nullptr,
        dt_proj_b, DTRANK);

    // K5-7: chunked scan (64 chunks x 32 steps)
    scan_phaseA<<<dim3(DINNER / 256, NCHUNK, BSZ), 256, 0, stream>>>(
        xdbl, dltbf, xtbf, A_log, Pbuf, Sbuf);
    scan_phaseB<<<NROW16 / 256, 256, 0, stream>>>(Pbuf, Sbuf, Hbuf);
    scan_phaseC<<<dim3(DINNER / 256, NCHUNK, BSZ), 256, 0, stream>>>(
        xdbl, dltbf, xtbf, zbf, A_log, Dvec, Hbuf, ybf);

    // K8: out = y @ out_proj_w^T (128x64 tile, 512 blocks)
    gemm_n64<<<dim3(DMODEL / 64, M / 128), 256, 0, stream>>>(
        (const short*)ybf, (const short*)owbf, out, DMODEL, DINNER);
}